// Round 2
// baseline (1130.038 us; speedup 1.0000x reference)
//
#include <hip/hip_runtime.h>

#define C_IN  128
#define C_OUT 256
#define EPS_BN 1e-4f
#define NPART 256  // stats partial-reduction blocks (fixed grid)

// ---------------------------------------------------------------------------
// Deterministic pipeline (no float atomics, no memset nodes, kernels only):
//  0. zero:   zero ocnt[N] + gcnt16[16] + cursor16[16].
//  1. count:  slot = atomicAdd(ocnt[out]) in 0..3 (max 4 contributors per
//             output, guaranteed by 2x2 window geometry). j = slot*4+tap.
//             Per-block LDS aggregation -> gcnt16[j]. Record slotj[i]=j.
//  2. prefix: base16 = exclusive prefix of gcnt16 (single thread, 16 entries).
//  3. fill:   scatter input ids into lists[base16[j]..) (LDS-aggregated).
//  4. conv slot 0: plain float4 stores (each output row written exactly once).
//     conv slots 1..3: read-modify-write (outputs unique within a slot;
//     dispatch serialization orders slots). No atomics, no races.
//  5. stats:  256 fixed blocks write per-channel partial sum/sumsq.
//  6. finalize: reduce partials, compute scale/shift (deterministic).
//  7. bnrelu: in-place normalize+relu rows < n_out; zero rows >= n_out.
// yconv lives in d_out (exact size); d_ws use ~3.7 MB.
// ---------------------------------------------------------------------------

__global__ __launch_bounds__(256) void zero_kernel(int* __restrict__ p, int n) {
  for (int i = blockIdx.x * 256 + threadIdx.x; i < n; i += gridDim.x * 256) p[i] = 0;
}

__global__ __launch_bounds__(256) void count_kernel(
    const int* __restrict__ offset, const int* __restrict__ out_index, int N,
    int* __restrict__ ocnt, int* __restrict__ gcnt16, int* __restrict__ slotj) {
  __shared__ int lc[16];
  const int t = threadIdx.x;
  if (t < 16) lc[t] = 0;
  __syncthreads();
  const int i = blockIdx.x * 256 + t;
  if (i < N) {
    const int o = out_index[i];
    const int slot = atomicAdd(&ocnt[o], 1);  // 0..3 by construction
    const int j = slot * 4 + offset[i];
    slotj[i] = j;
    atomicAdd(&lc[j], 1);
  }
  __syncthreads();
  if (t < 16 && lc[t]) atomicAdd(&gcnt16[t], lc[t]);
}

__global__ void prefix_kernel(const int* __restrict__ gcnt16, int* __restrict__ base16) {
  if (threadIdx.x == 0) {
    int acc = 0;
    for (int j = 0; j < 16; ++j) { base16[j] = acc; acc += gcnt16[j]; }
  }
}

__global__ __launch_bounds__(256) void fill_kernel(
    const int* __restrict__ slotj, int N, int* __restrict__ cursor16,
    const int* __restrict__ base16, int* __restrict__ lists) {
  __shared__ int lc[16];
  __shared__ int lb[16];
  const int t = threadIdx.x;
  if (t < 16) lc[t] = 0;
  __syncthreads();
  const int i = blockIdx.x * 256 + t;
  int j = -1, mypos = 0;
  if (i < N) {
    j = slotj[i];
    mypos = atomicAdd(&lc[j], 1);
  }
  __syncthreads();
  if (t < 16) lb[t] = lc[t] ? atomicAdd(&cursor16[t], lc[t]) : 0;
  __syncthreads();
  if (j >= 0) lists[base16[j] + lb[j] + mypos] = i;
}

// Tile: 32 rows x 256 cols, K=128, grid-stride over tiles, one tap per blockIdx.y.
// RMW=0 (slot 0): plain stores. RMW=1 (slots>=1): load+add+store, race-free
// because outputs are unique within a slot and slots are separate dispatches.
template <int RMW>
__global__ __launch_bounds__(256, 4) void conv_kernel(
    const float* __restrict__ x, const float* __restrict__ W,
    const int* __restrict__ lists, const int* __restrict__ gcnt16,
    const int* __restrict__ base16, const int* __restrict__ out_index,
    float* __restrict__ yconv, int slot) {
  const int tap = blockIdx.y;
  const int j = slot * 4 + tap;
  const int cnt = gcnt16[j];
  const int* __restrict__ list = lists + base16[j];
  const float* __restrict__ Wt = W + (size_t)tap * C_IN * C_OUT;

  __shared__ alignas(16) float xs[C_IN][36];  // [k][r], 144B row stride
  __shared__ int rowid[32];
  __shared__ int orow[32];

  const int tid = threadIdx.x;
  const int tc = tid & 31;  // cols tc*4..+3 and 128+tc*4..+3
  const int tr = tid >> 5;  // rows tr*4..+3

  for (int m0 = blockIdx.x * 32; m0 < cnt; m0 += gridDim.x * 32) {
    __syncthreads();  // protect LDS from previous iteration's readers
    if (tid < 32) {
      const int idx = m0 + tid;
      const int src = list[idx < cnt ? idx : cnt - 1];  // clamp (stores guarded)
      rowid[tid] = src;
      orow[tid] = out_index[src];
    }
    __syncthreads();
    {  // stage x tile transposed: thread t loads row t/8, 16 cols from (t%8)*16
      const int r = tid >> 3, p = tid & 7;
      const float4* xrow = (const float4*)(x + (size_t)rowid[r] * C_IN);
#pragma unroll
      for (int jj = 0; jj < 4; ++jj) {
        const float4 v = xrow[p * 4 + jj];
        const int kk = p * 16 + jj * 4;
        xs[kk + 0][r] = v.x;
        xs[kk + 1][r] = v.y;
        xs[kk + 2][r] = v.z;
        xs[kk + 3][r] = v.w;
      }
    }
    __syncthreads();

    float acc[4][8];
#pragma unroll
    for (int i2 = 0; i2 < 4; ++i2)
#pragma unroll
      for (int jj = 0; jj < 8; ++jj) acc[i2][jj] = 0.f;

    const float* wp = Wt + tc * 4;
    const float* xsp = &xs[0][tr * 4];
#pragma unroll 2
    for (int k = 0; k < C_IN; ++k) {
      const float4 xv = *(const float4*)(xsp + k * 36);
      const float4 wa = *(const float4*)(wp);
      const float4 wb = *(const float4*)(wp + 128);
      wp += C_OUT;
      const float xr[4] = {xv.x, xv.y, xv.z, xv.w};
      const float wr[8] = {wa.x, wa.y, wa.z, wa.w, wb.x, wb.y, wb.z, wb.w};
#pragma unroll
      for (int i2 = 0; i2 < 4; ++i2)
#pragma unroll
        for (int jj = 0; jj < 8; ++jj)
          acc[i2][jj] = fmaf(xr[i2], wr[jj], acc[i2][jj]);
    }

#pragma unroll
    for (int i2 = 0; i2 < 4; ++i2) {
      const int r = tr * 4 + i2;
      if (m0 + r >= cnt) continue;
      float* dst = yconv + (size_t)orow[r] * C_OUT;
      float4 a = make_float4(acc[i2][0], acc[i2][1], acc[i2][2], acc[i2][3]);
      float4 b = make_float4(acc[i2][4], acc[i2][5], acc[i2][6], acc[i2][7]);
      if (RMW) {
        const float4 o0 = *(const float4*)(dst + tc * 4);
        const float4 o1 = *(const float4*)(dst + 128 + tc * 4);
        a.x += o0.x; a.y += o0.y; a.z += o0.z; a.w += o0.w;
        b.x += o1.x; b.y += o1.y; b.z += o1.z; b.w += o1.w;
      }
      *(float4*)(dst + tc * 4) = a;
      *(float4*)(dst + 128 + tc * 4) = b;
    }
  }
}

__global__ __launch_bounds__(256) void stats_kernel(
    const float* __restrict__ yconv, const int* __restrict__ gcnt16,
    float* __restrict__ partials) {
  const int n_out = gcnt16[0] + gcnt16[1] + gcnt16[2] + gcnt16[3];
  const int c = threadIdx.x;
  float s1 = 0.f, s2 = 0.f;
  for (int row = blockIdx.x; row < n_out; row += gridDim.x) {
    const float v = yconv[(size_t)row * C_OUT + c];
    s1 += v;
    s2 = fmaf(v, v, s2);
  }
  partials[blockIdx.x * 512 + c] = s1;
  partials[blockIdx.x * 512 + 256 + c] = s2;
}

__global__ __launch_bounds__(256) void finalize_kernel(
    const float* __restrict__ partials, const int* __restrict__ gcnt16,
    const float* __restrict__ gamma, const float* __restrict__ beta,
    float* __restrict__ ss) {
  const int n_out = gcnt16[0] + gcnt16[1] + gcnt16[2] + gcnt16[3];
  const float cntf = (float)n_out;
  const int c = threadIdx.x;
  float s1 = 0.f, s2 = 0.f;
  for (int b = 0; b < NPART; ++b) {
    s1 += partials[b * 512 + c];
    s2 += partials[b * 512 + 256 + c];
  }
  const float mean = s1 / cntf;
  const float var = s2 / cntf - mean * mean;
  const float sc = rsqrtf(var + EPS_BN) * gamma[c];
  ss[c] = sc;
  ss[C_OUT + c] = beta[c] - mean * sc;
}

__global__ __launch_bounds__(256) void bnrelu_kernel(
    float* __restrict__ out, const float* __restrict__ ss,
    const int* __restrict__ gcnt16, int N) {
  __shared__ float lss[2 * C_OUT];
  const int t = threadIdx.x;
  lss[t] = ss[t];
  lss[t + 256] = ss[t + 256];
  __syncthreads();
  const size_t n_out = (size_t)(gcnt16[0] + gcnt16[1] + gcnt16[2] + gcnt16[3]);
  const size_t total = (size_t)N * (C_OUT / 4);
  float4* o4 = (float4*)out;
  for (size_t idx = (size_t)blockIdx.x * 256 + t; idx < total;
       idx += (size_t)gridDim.x * 256) {
    const size_t row = idx >> 6;
    const int c4 = ((int)idx & 63) * 4;
    float4 r;
    if (row < n_out) {
      const float4 v = o4[idx];
      r.x = fmaxf(fmaf(v.x, lss[c4 + 0], lss[256 + c4 + 0]), 0.f);
      r.y = fmaxf(fmaf(v.y, lss[c4 + 1], lss[256 + c4 + 1]), 0.f);
      r.z = fmaxf(fmaf(v.z, lss[c4 + 2], lss[256 + c4 + 2]), 0.f);
      r.w = fmaxf(fmaf(v.w, lss[c4 + 3], lss[256 + c4 + 3]), 0.f);
    } else {
      r = make_float4(0.f, 0.f, 0.f, 0.f);
    }
    o4[idx] = r;
  }
}

extern "C" void kernel_launch(void* const* d_in, const int* in_sizes, int n_in,
                              void* d_out, int out_size, void* d_ws, size_t ws_size,
                              hipStream_t stream) {
  const float* x = (const float*)d_in[0];
  const float* W = (const float*)d_in[1];
  const float* gamma = (const float*)d_in[2];
  const float* beta = (const float*)d_in[3];
  const int* offset = (const int*)d_in[4];
  const int* out_index = (const int*)d_in[5];
  // d_in[6] (out_mask) unused: mask == (row < n_out), n_out derived on device.
  const int N = in_sizes[0] / C_IN;
  float* yconv = (float*)d_out;

  // ws layout (bytes):
  char* ws = (char*)d_ws;
  int* ocnt = (int*)ws;                              // N ints
  int* gcnt16 = (int*)(ws + (size_t)N * 4);          // 16 ints
  int* cursor16 = gcnt16 + 16;                       // 16 ints (zeroed with ocnt)
  int* base16 = gcnt16 + 32;                         // 16 ints (fully written)
  char* p = ws + (size_t)N * 4 + 256;
  int* slotj = (int*)p;                              // N ints (fully written)
  int* lists = (int*)(p + (size_t)N * 4);            // N ints
  float* partials = (float*)(p + (size_t)N * 8);     // NPART*512 floats
  float* ss = partials + NPART * 512;                // 512 floats

  zero_kernel<<<256, 256, 0, stream>>>(ocnt, N + 32);  // ocnt + gcnt16 + cursor16
  count_kernel<<<(N + 255) / 256, 256, 0, stream>>>(offset, out_index, N,
                                                    ocnt, gcnt16, slotj);
  prefix_kernel<<<1, 64, 0, stream>>>(gcnt16, base16);
  fill_kernel<<<(N + 255) / 256, 256, 0, stream>>>(slotj, N, cursor16, base16, lists);

  conv_kernel<0><<<dim3(512, 4), 256, 0, stream>>>(x, W, lists, gcnt16, base16,
                                                   out_index, yconv, 0);
  conv_kernel<1><<<dim3(64, 4), 256, 0, stream>>>(x, W, lists, gcnt16, base16,
                                                  out_index, yconv, 1);
  conv_kernel<1><<<dim3(16, 4), 256, 0, stream>>>(x, W, lists, gcnt16, base16,
                                                  out_index, yconv, 2);
  conv_kernel<1><<<dim3(4, 4), 256, 0, stream>>>(x, W, lists, gcnt16, base16,
                                                 out_index, yconv, 3);

  stats_kernel<<<NPART, 256, 0, stream>>>(yconv, gcnt16, partials);
  finalize_kernel<<<1, 256, 0, stream>>>(partials, gcnt16, gamma, beta, ss);
  bnrelu_kernel<<<2048, 256, 0, stream>>>(yconv, ss, gcnt16, N);
}

// Round 3
// 857.252 us; speedup vs baseline: 1.3182x; 1.3182x over previous
//
#include <hip/hip_runtime.h>

#define C_IN  128
#define C_OUT 256
#define EPS_BN 1e-4f
#define NPART 256

typedef __attribute__((ext_vector_type(8))) short bf16x8;
typedef __attribute__((ext_vector_type(4))) float f32x4;

__device__ __forceinline__ ushort f2bf(float f) {
  union { float f; unsigned u; } c; c.f = f;
  const unsigned u = c.u;
  return (ushort)((u + 0x7FFF + ((u >> 16) & 1)) >> 16);  // RNE
}

// ---------------------------------------------------------------------------
// Pipeline (deterministic, no float atomics, kernels only):
//  zero -> count (slot=atomicAdd per output, 0..3) -> prefix -> fill lists
//  packW: W f32 -> bf16 B-fragment layout (one dwordx4 per frag per lane)
//  conv slot0: MFMA 32x256 tiles, plain stores (unique outputs)
//  conv slots1-3: same, read-modify-write (unique within slot, slots serialized)
//  stats -> finalize -> bnrelu (in-place, zero padding rows)
// ---------------------------------------------------------------------------

__global__ __launch_bounds__(256) void zero_kernel(int* __restrict__ p, int n) {
  for (int i = blockIdx.x * 256 + threadIdx.x; i < n; i += gridDim.x * 256) p[i] = 0;
}

__global__ __launch_bounds__(256) void count_kernel(
    const int* __restrict__ offset, const int* __restrict__ out_index, int N,
    int* __restrict__ ocnt, int* __restrict__ gcnt16, int* __restrict__ slotj) {
  __shared__ int lc[16];
  const int t = threadIdx.x;
  if (t < 16) lc[t] = 0;
  __syncthreads();
  const int i = blockIdx.x * 256 + t;
  if (i < N) {
    const int o = out_index[i];
    const int slot = atomicAdd(&ocnt[o], 1);  // 0..3 by 2x2-window geometry
    const int j = slot * 4 + offset[i];
    slotj[i] = j;
    atomicAdd(&lc[j], 1);
  }
  __syncthreads();
  if (t < 16 && lc[t]) atomicAdd(&gcnt16[t], lc[t]);
}

__global__ void prefix_kernel(const int* __restrict__ gcnt16, int* __restrict__ base16) {
  if (threadIdx.x == 0) {
    int acc = 0;
    for (int j = 0; j < 16; ++j) { base16[j] = acc; acc += gcnt16[j]; }
  }
}

__global__ __launch_bounds__(256) void fill_kernel(
    const int* __restrict__ slotj, int N, int* __restrict__ cursor16,
    const int* __restrict__ base16, int* __restrict__ lists) {
  __shared__ int lc[16];
  __shared__ int lb[16];
  const int t = threadIdx.x;
  if (t < 16) lc[t] = 0;
  __syncthreads();
  const int i = blockIdx.x * 256 + t;
  int j = -1, mypos = 0;
  if (i < N) {
    j = slotj[i];
    mypos = atomicAdd(&lc[j], 1);
  }
  __syncthreads();
  if (t < 16) lb[t] = lc[t] ? atomicAdd(&cursor16[t], lc[t]) : 0;
  __syncthreads();
  if (j >= 0) lists[base16[j] + lb[j] + mypos] = i;
}

// W[tap][k][c] f32 -> Wp B-fragments: id=(tap,ks,nt,lane), elem j:
//   n = nt*16 + (lane&15), k = ks*32 + (lane>>4)*8 + j
__global__ __launch_bounds__(256) void packW_kernel(
    const float* __restrict__ W, ushort* __restrict__ Wp) {
  const int id = blockIdx.x * 256 + threadIdx.x;  // 0..16383
  const int lane = id & 63;
  const int nt = (id >> 6) & 15;
  const int ks = (id >> 10) & 3;
  const int tap = id >> 12;
  const int col = nt * 16 + (lane & 15);
  const int k0 = ks * 32 + (lane >> 4) * 8;
  struct alignas(16) U8 { ushort u[8]; } h;
#pragma unroll
  for (int i = 0; i < 8; ++i)
    h.u[i] = f2bf(W[((size_t)tap * C_IN + (k0 + i)) * C_OUT + col]);
  *(U8*)(Wp + (size_t)id * 8) = h;
}

// MFMA tile: 32 rows x 256 cols, K=128. 4 waves, wave w -> cols w*64..+63.
// B-frags (16 per wave) hoisted into registers for the whole kernel.
template <int RMW>
__global__ __launch_bounds__(256) void conv_mfma_kernel(
    const float* __restrict__ x, const ushort* __restrict__ Wp,
    const int* __restrict__ lists, const int* __restrict__ gcnt16,
    const int* __restrict__ base16, const int* __restrict__ out_index,
    float* __restrict__ yconv, int slot) {
  const int tap = blockIdx.y;
  const int j = slot * 4 + tap;
  const int cnt = gcnt16[j];
  const int* __restrict__ list = lists + base16[j];

  __shared__ alignas(16) ushort xs[4][2][64][8];  // [ks][mt][lane][8] = 8KB
  __shared__ int rowid[32];
  __shared__ int orow[32];

  const int tid = threadIdx.x;
  const int wv = tid >> 6;
  const int lane = tid & 63;

  bf16x8 B[4][4];
#pragma unroll
  for (int ks = 0; ks < 4; ++ks)
#pragma unroll
    for (int jn = 0; jn < 4; ++jn)
      B[ks][jn] = *(const bf16x8*)(Wp + ((((size_t)tap * 4 + ks) * 16 + wv * 4 + jn) * 64 + lane) * 8);

  const int r_stage = tid >> 3;          // row 0..31
  const int p_stage = tid & 7;           // 16-float chunk 0..7
  const int ks_st = p_stage >> 1;
  const int mt_st = r_stage >> 4;
  const int laneA0 = (r_stage & 15) + 32 * (p_stage & 1);

  const int colb = lane & 15;
  const int rsub = (lane >> 4) * 4;

  for (int m0 = blockIdx.x * 32; m0 < cnt; m0 += gridDim.x * 32) {
    __syncthreads();
    if (tid < 32) {
      const int idx = m0 + tid;
      const int src = list[idx < cnt ? idx : cnt - 1];  // clamp tail; stores guarded
      rowid[tid] = src;
      orow[tid] = out_index[src];
    }
    __syncthreads();
    {  // stage + f32->bf16 + pack into A-fragment layout
      const float4* xr = (const float4*)(x + (size_t)rowid[r_stage] * C_IN) + p_stage * 4;
      const float4 v0 = xr[0], v1 = xr[1], v2 = xr[2], v3 = xr[3];
      struct alignas(16) U8 { ushort u[8]; } a, b;
      a.u[0] = f2bf(v0.x); a.u[1] = f2bf(v0.y); a.u[2] = f2bf(v0.z); a.u[3] = f2bf(v0.w);
      a.u[4] = f2bf(v1.x); a.u[5] = f2bf(v1.y); a.u[6] = f2bf(v1.z); a.u[7] = f2bf(v1.w);
      b.u[0] = f2bf(v2.x); b.u[1] = f2bf(v2.y); b.u[2] = f2bf(v2.z); b.u[3] = f2bf(v2.w);
      b.u[4] = f2bf(v3.x); b.u[5] = f2bf(v3.y); b.u[6] = f2bf(v3.z); b.u[7] = f2bf(v3.w);
      *(U8*)&xs[ks_st][mt_st][laneA0][0] = a;
      *(U8*)&xs[ks_st][mt_st][laneA0 + 16][0] = b;
    }
    __syncthreads();

    f32x4 acc[2][4] = {};
#pragma unroll
    for (int ks = 0; ks < 4; ++ks) {
      const bf16x8 A0 = *(const bf16x8*)&xs[ks][0][lane][0];
      const bf16x8 A1 = *(const bf16x8*)&xs[ks][1][lane][0];
#pragma unroll
      for (int jn = 0; jn < 4; ++jn) {
        acc[0][jn] = __builtin_amdgcn_mfma_f32_16x16x32_bf16(A0, B[ks][jn], acc[0][jn], 0, 0, 0);
        acc[1][jn] = __builtin_amdgcn_mfma_f32_16x16x32_bf16(A1, B[ks][jn], acc[1][jn], 0, 0, 0);
      }
    }

#pragma unroll
    for (int mt = 0; mt < 2; ++mt)
#pragma unroll
      for (int reg = 0; reg < 4; ++reg) {
        const int r = mt * 16 + rsub + reg;
        if (m0 + r < cnt) {
          float* dst = yconv + (size_t)orow[r] * C_OUT + wv * 64 + colb;
#pragma unroll
          for (int jn = 0; jn < 4; ++jn) {
            float v = acc[mt][jn][reg];
            if (RMW) v += dst[jn * 16];
            dst[jn * 16] = v;
          }
        }
      }
  }
}

__global__ __launch_bounds__(256) void stats_kernel(
    const float* __restrict__ yconv, const int* __restrict__ gcnt16,
    float* __restrict__ partials) {
  const int n_out = gcnt16[0] + gcnt16[1] + gcnt16[2] + gcnt16[3];
  const int c = threadIdx.x;
  float s1 = 0.f, s2 = 0.f;
  for (int row = blockIdx.x; row < n_out; row += gridDim.x) {
    const float v = yconv[(size_t)row * C_OUT + c];
    s1 += v;
    s2 = fmaf(v, v, s2);
  }
  partials[blockIdx.x * 512 + c] = s1;
  partials[blockIdx.x * 512 + 256 + c] = s2;
}

__global__ __launch_bounds__(256) void finalize_kernel(
    const float* __restrict__ partials, const int* __restrict__ gcnt16,
    const float* __restrict__ gamma, const float* __restrict__ beta,
    float* __restrict__ ss) {
  const int n_out = gcnt16[0] + gcnt16[1] + gcnt16[2] + gcnt16[3];
  const float cntf = (float)n_out;
  const int c = threadIdx.x;
  float s1 = 0.f, s2 = 0.f;
  for (int b = 0; b < NPART; ++b) {
    s1 += partials[b * 512 + c];
    s2 += partials[b * 512 + 256 + c];
  }
  const float mean = s1 / cntf;
  const float var = s2 / cntf - mean * mean;
  const float sc = rsqrtf(var + EPS_BN) * gamma[c];
  ss[c] = sc;
  ss[C_OUT + c] = beta[c] - mean * sc;
}

__global__ __launch_bounds__(256) void bnrelu_kernel(
    float* __restrict__ out, const float* __restrict__ ss,
    const int* __restrict__ gcnt16, int N) {
  __shared__ float lss[2 * C_OUT];
  const int t = threadIdx.x;
  lss[t] = ss[t];
  lss[t + 256] = ss[t + 256];
  __syncthreads();
  const size_t n_out = (size_t)(gcnt16[0] + gcnt16[1] + gcnt16[2] + gcnt16[3]);
  const size_t total = (size_t)N * (C_OUT / 4);
  float4* o4 = (float4*)out;
  for (size_t idx = (size_t)blockIdx.x * 256 + t; idx < total;
       idx += (size_t)gridDim.x * 256) {
    const size_t row = idx >> 6;
    const int c4 = ((int)idx & 63) * 4;
    float4 r;
    if (row < n_out) {
      const float4 v = o4[idx];
      r.x = fmaxf(fmaf(v.x, lss[c4 + 0], lss[256 + c4 + 0]), 0.f);
      r.y = fmaxf(fmaf(v.y, lss[c4 + 1], lss[256 + c4 + 1]), 0.f);
      r.z = fmaxf(fmaf(v.z, lss[c4 + 2], lss[256 + c4 + 2]), 0.f);
      r.w = fmaxf(fmaf(v.w, lss[c4 + 3], lss[256 + c4 + 3]), 0.f);
    } else {
      r = make_float4(0.f, 0.f, 0.f, 0.f);
    }
    o4[idx] = r;
  }
}

extern "C" void kernel_launch(void* const* d_in, const int* in_sizes, int n_in,
                              void* d_out, int out_size, void* d_ws, size_t ws_size,
                              hipStream_t stream) {
  const float* x = (const float*)d_in[0];
  const float* W = (const float*)d_in[1];
  const float* gamma = (const float*)d_in[2];
  const float* beta = (const float*)d_in[3];
  const int* offset = (const int*)d_in[4];
  const int* out_index = (const int*)d_in[5];
  const int N = in_sizes[0] / C_IN;
  float* yconv = (float*)d_out;

  char* ws = (char*)d_ws;
  int* ocnt = (int*)ws;                               // N ints
  int* gcnt16 = (int*)(ws + (size_t)N * 4);           // 16
  int* cursor16 = gcnt16 + 16;                        // 16 (zeroed with ocnt)
  int* base16 = gcnt16 + 32;                          // 16 (fully written)
  char* p = ws + (size_t)N * 4 + 256;
  int* slotj = (int*)p;                               // N ints
  int* lists = (int*)(p + (size_t)N * 4);             // N ints
  float* partials = (float*)(p + (size_t)N * 8);      // NPART*512 floats
  float* ss = partials + NPART * 512;                 // 512 floats
  ushort* Wp = (ushort*)(ss + 512);                   // 4*128*256 bf16 = 256KB

  zero_kernel<<<256, 256, 0, stream>>>(ocnt, N + 32);
  packW_kernel<<<64, 256, 0, stream>>>(W, Wp);
  count_kernel<<<(N + 255) / 256, 256, 0, stream>>>(offset, out_index, N,
                                                    ocnt, gcnt16, slotj);
  prefix_kernel<<<1, 64, 0, stream>>>(gcnt16, base16);
  fill_kernel<<<(N + 255) / 256, 256, 0, stream>>>(slotj, N, cursor16, base16, lists);

  conv_mfma_kernel<0><<<dim3(1024, 4), 256, 0, stream>>>(x, Wp, lists, gcnt16, base16,
                                                         out_index, yconv, 0);
  conv_mfma_kernel<1><<<dim3(256, 4), 256, 0, stream>>>(x, Wp, lists, gcnt16, base16,
                                                        out_index, yconv, 1);
  conv_mfma_kernel<1><<<dim3(64, 4), 256, 0, stream>>>(x, Wp, lists, gcnt16, base16,
                                                       out_index, yconv, 2);
  conv_mfma_kernel<1><<<dim3(64, 4), 256, 0, stream>>>(x, Wp, lists, gcnt16, base16,
                                                       out_index, yconv, 3);

  stats_kernel<<<NPART, 256, 0, stream>>>(yconv, gcnt16, partials);
  finalize_kernel<<<1, 256, 0, stream>>>(partials, gcnt16, gamma, beta, ss);
  bnrelu_kernel<<<2048, 256, 0, stream>>>(yconv, ss, gcnt16, N);
}